// Round 10
// baseline (864.488 us; speedup 1.0000x reference)
//
#include <hip/hip_runtime.h>
#include <hip/hip_fp16.h>

// Problem constants (fixed by the reference)
constexpr int Bb = 32;     // batch
constexpr int Tt = 32;     // time steps
constexpr int Ii = 8192;   // input dim
constexpr int Hh = 8192;   // hidden dim
constexpr int Oo = 2048;   // output dim
constexpr int TB = Tt * Bb;  // halves per x2 column = 1024
constexpr int TCH = 4;       // timesteps per XCD chunk

// Entry packing: lo16 = col (u16), hi16 = fp16 value bits. 4 B/entry.
// Rows padded to multiples of 8 entries (32 B) -> int4 loads cover 4 entries.

__device__ __forceinline__ float entval(uint32_t u) {
  return __half2float(__ushort_as_half((unsigned short)(u >> 16)));
}
__device__ __forceinline__ uint32_t entpack(float v, int c) {
  return ((uint32_t)__half_as_ushort(__float2half_rn(v)) << 16) | (uint32_t)c;
}

// ---------------- K1: XCD-filtered histogram (512 blocks) ‖ x transpose (2048) ----------------
constexpr int SCB = 512;   // scatter/hist block count (64 per XCD)
__global__ void __launch_bounds__(256) k1_hist_transpose(
    const float* __restrict__ x, __half2* __restrict__ x2,
    const int* __restrict__ ihr, int n_ih, int* __restrict__ ih_c,
    const int* __restrict__ hhr, int n_hh, int* __restrict__ hh_c,
    const int* __restrict__ hor, int n_ho, int* __restrict__ ho_c) {
  if (blockIdx.x < SCB) {
    // Per-XCD row-ownership filter keeps counter lines pinned to one L2.
    int xcd = blockIdx.x & 7;
    int base = (blockIdx.x >> 3) * 256 + threadIdx.x;
    int stride = (SCB >> 3) * 256;   // 16384
    for (int j = base; j < n_ih; j += stride) {
      int r = ihr[j];
      if ((r >> 10) == xcd) atomicAdd(&ih_c[r], 1);
    }
    for (int j = base; j < n_hh; j += stride) {
      int r = hhr[j];
      if ((r >> 10) == xcd) atomicAdd(&hh_c[r], 1);
    }
    for (int j = base; j < n_ho; j += stride) {
      int r = hor[j];
      if ((r >> 8) == xcd) atomicAdd(&ho_c[r], 1);
    }
  } else {
    int tb = blockIdx.x - SCB;       // 2048 transpose blocks
    int tp = tb >> 7;
    int ib = tb & 127;
    int t0 = tp * 2;
    int i0 = ib * 64;
    __shared__ float lds[64][65];
    int tid = threadIdx.x;
    for (int idx = tid; idx < 64 * 64; idx += 256) {
      int row = idx >> 6, il = idx & 63;   // coalesced reads along i
      int tt = row >> 5, bb = row & 31;
      lds[il][row] = x[(size_t)bb * Tt * Ii + (size_t)(t0 + tt) * Ii + i0 + il];
    }
    __syncthreads();
    for (int idx = tid; idx < 64 * 32; idx += 256) {
      int il = idx >> 5;
      int q = idx & 31;
      int tt = q >> 4, p = q & 15;
      float lo = lds[il][tt * 32 + 2 * p];
      float hi = lds[il][tt * 32 + 2 * p + 1];
      x2[(size_t)(i0 + il) * (TB / 2) + (size_t)(t0 + tt) * 16 + p] = __floats2half2_rn(lo, hi);
    }
  }
}

// ---------------- K2: scan (rows padded to multiples of 8 entries) ----------------
__global__ void scan3_kernel(int* __restrict__ c1, int n1, int* __restrict__ r1,
                             int* __restrict__ c2, int n2, int* __restrict__ r2,
                             int* __restrict__ c3, int n3, int* __restrict__ r3) {
  int* cnt_cursor; int n; int* row_start;
  if (blockIdx.x == 0)      { cnt_cursor = c1; n = n1; row_start = r1; }
  else if (blockIdx.x == 1) { cnt_cursor = c2; n = n2; row_start = r2; }
  else                      { cnt_cursor = c3; n = n3; row_start = r3; }
  __shared__ int sums[1024];
  int tid = threadIdx.x;
  int chunk = (n + 1023) >> 10;
  int base = tid * chunk;
  int s = 0;
  for (int i = 0; i < chunk; i++) {
    int idx = base + i;
    if (idx < n) s += (cnt_cursor[idx] + 7) & ~7;
  }
  sums[tid] = s;
  __syncthreads();
  for (int off = 1; off < 1024; off <<= 1) {
    int other = (tid >= off) ? sums[tid - off] : 0;
    __syncthreads();
    sums[tid] += other;
    __syncthreads();
  }
  int run = sums[tid] - s;
  for (int i = 0; i < chunk; i++) {
    int idx = base + i;
    if (idx < n) {
      int v = cnt_cursor[idx];
      row_start[idx] = run;
      cnt_cursor[idx] = run;
      run += (v + 7) & ~7;
    }
  }
  if (tid == 1023) row_start[n] = sums[1023];
}

// ---------------- K3: XCD-filtered ih scatter (critical path to preih) ----------------
__global__ void __launch_bounds__(256) k3_scatter_ih(
    const int* __restrict__ ihr, const int* __restrict__ ihc, const float* __restrict__ ihv,
    int n, int* __restrict__ cu, uint32_t* __restrict__ e) {
  int xcd = blockIdx.x & 7;
  int base = (blockIdx.x >> 3) * 256 + threadIdx.x;
  int stride = (SCB >> 3) * 256;
  for (int j = base; j < n; j += stride) {
    int r = ihr[j];
    if ((r >> 10) == xcd) {
      int pos = atomicAdd(&cu[r], 1);
      e[pos] = entpack(ihv[j], ihc[j]);
    }
  }
}

// ---------------- K4: XCD-filtered hh+ho scatter (512 blocks, first) ‖ preih (16384) ----------------
// preih: xcd = pb&7 owns t-chunk [4*xcd,4*xcd+4): 2 MB fp16 x2 slice L2-resident.
// Scatter: each XCD writes only its dense 1/8 row-slice of entries -> no write amp.
__global__ void __launch_bounds__(256, 8) k4_preih_scatter(
    const int* __restrict__ ih_rs, const int* __restrict__ ih_cur,
    const uint32_t* __restrict__ ih_ent,
    const float* __restrict__ hh_bias, const __half* __restrict__ x2h,
    __half2* __restrict__ preAll,
    const int* __restrict__ hhr, const int* __restrict__ hhc, const float* __restrict__ hhv,
    int n_hh, int* __restrict__ hh_cu, uint32_t* __restrict__ hh_e,
    const int* __restrict__ hor, const int* __restrict__ hoc, const float* __restrict__ hov,
    int n_ho, int* __restrict__ ho_cu, uint32_t* __restrict__ ho_e) {
  if (blockIdx.x < SCB) {
    int xcd = blockIdx.x & 7;
    int base = (blockIdx.x >> 3) * 256 + threadIdx.x;
    int stride = (SCB >> 3) * 256;
    for (int j = base; j < n_hh; j += stride) {
      int r = hhr[j];
      if ((r >> 10) == xcd) {
        int pos = atomicAdd(&hh_cu[r], 1);
        hh_e[pos] = entpack(hhv[j], hhc[j]);
      }
    }
    for (int j = base; j < n_ho; j += stride) {
      int r = hor[j];
      if ((r >> 8) == xcd) {
        int pos = atomicAdd(&ho_cu[r], 1);
        ho_e[pos] = entpack(hov[j], hoc[j]);
      }
    }
    return;
  }
  int pb = blockIdx.x - SCB;
  int xcd = pb & 7;
  int r = ((pb >> 3) << 2) + (threadIdx.x >> 6);
  int lane = threadIdx.x & 63;
  int t0 = xcd * TCH;
  int s0  = __builtin_amdgcn_readfirstlane(ih_rs[r]);       // multiple of 8
  int cnt = __builtin_amdgcn_readfirstlane(ih_cur[r]) - s0;
  int nb = (cnt + 7) >> 3;
  const int4* ep = (const int4*)(ih_ent + s0);
  const uint32_t* xb = (const uint32_t*)(x2h + (size_t)t0 * Bb);

  float2 a0 = {0.f, 0.f}, a1 = {0.f, 0.f}, a2 = {0.f, 0.f}, a3 = {0.f, 0.f};
  int4 f0 = ep[0], f1 = ep[1];
  for (int i = 0; i < nb; i++) {
    int4 e0 = f0, e1 = f1;
    f0 = ep[2 * i + 2];
    f1 = ep[2 * i + 3];
    uint32_t u0 = (uint32_t)e0.x, u1 = (uint32_t)e0.y, u2 = (uint32_t)e0.z, u3 = (uint32_t)e0.w;
    uint32_t u4 = (uint32_t)e1.x, u5 = (uint32_t)e1.y, u6 = (uint32_t)e1.z, u7 = (uint32_t)e1.w;
    uint32_t g0 = xb[(size_t)(u0 & 0xffff) * (TB / 2) + lane];
    uint32_t g1 = xb[(size_t)(u1 & 0xffff) * (TB / 2) + lane];
    uint32_t g2 = xb[(size_t)(u2 & 0xffff) * (TB / 2) + lane];
    uint32_t g3 = xb[(size_t)(u3 & 0xffff) * (TB / 2) + lane];
    uint32_t g4 = xb[(size_t)(u4 & 0xffff) * (TB / 2) + lane];
    uint32_t g5 = xb[(size_t)(u5 & 0xffff) * (TB / 2) + lane];
    uint32_t g6 = xb[(size_t)(u6 & 0xffff) * (TB / 2) + lane];
    uint32_t g7 = xb[(size_t)(u7 & 0xffff) * (TB / 2) + lane];
    float v0 = entval(u0), v1 = entval(u1), v2 = entval(u2), v3 = entval(u3);
    float v4 = entval(u4), v5 = entval(u5), v6 = entval(u6), v7 = entval(u7);
    float2 x0 = __half22float2(*(__half2*)&g0), x1 = __half22float2(*(__half2*)&g1);
    float2 x2v = __half22float2(*(__half2*)&g2), x3 = __half22float2(*(__half2*)&g3);
    float2 x4 = __half22float2(*(__half2*)&g4), x5 = __half22float2(*(__half2*)&g5);
    float2 x6 = __half22float2(*(__half2*)&g6), x7 = __half22float2(*(__half2*)&g7);
    a0.x += v0 * x0.x;  a0.y += v0 * x0.y;   a0.x += v4 * x4.x;  a0.y += v4 * x4.y;
    a1.x += v1 * x1.x;  a1.y += v1 * x1.y;   a1.x += v5 * x5.x;  a1.y += v5 * x5.y;
    a2.x += v2 * x2v.x; a2.y += v2 * x2v.y;  a2.x += v6 * x6.x;  a2.y += v6 * x6.y;
    a3.x += v3 * x3.x;  a3.y += v3 * x3.y;   a3.x += v7 * x7.x;  a3.y += v7 * x7.y;
  }
  float bias = hh_bias[r];
  float sx = ((a0.x + a1.x) + (a2.x + a3.x)) + bias;
  float sy = ((a0.y + a1.y) + (a2.y + a3.y)) + bias;
  int tt = lane >> 4, p = lane & 15;
  preAll[((size_t)(t0 + tt) * Hh + r) * 16 + p] = __floats2half2_rn(sx, sy);
}

// ---------------- One recurrence step: h_{t+1} = sigmoid(pre_t + HH @ h_t) ----------------
__global__ void __launch_bounds__(256, 8) step_kernel(
    const int* __restrict__ hh_rs, const int* __restrict__ hh_cur,
    const uint32_t* __restrict__ hh_ent,
    const __half* __restrict__ pre_t,
    const __half* __restrict__ hprev,
    __half* __restrict__ hnext) {
  int r = (blockIdx.x * 256 + threadIdx.x) >> 6;
  int lane = threadIdx.x & 63;
  int h = lane >> 5, b = lane & 31;
  int s0  = __builtin_amdgcn_readfirstlane(hh_rs[r]);
  int cnt = __builtin_amdgcn_readfirstlane(hh_cur[r]) - s0;
  int nb = (cnt + 7) >> 3;
  const int4* ep = (const int4*)(hh_ent + s0);
  float pre = __half2float(pre_t[(r << 5) + b]);

  float a0 = 0.f, a1 = 0.f, a2 = 0.f, a3 = 0.f;
  int4 f0 = ep[0], f1 = ep[1];
  for (int i = 0; i < nb; i++) {
    int4 e0 = f0, e1 = f1;
    f0 = ep[2 * i + 2];
    f1 = ep[2 * i + 3];
    uint32_t u0 = (uint32_t)(h ? e0.y : e0.x);
    uint32_t u1 = (uint32_t)(h ? e0.w : e0.z);
    uint32_t u2 = (uint32_t)(h ? e1.y : e1.x);
    uint32_t u3 = (uint32_t)(h ? e1.w : e1.z);
    float h0 = __half2float(hprev[(((size_t)(u0 & 0xffff)) << 5) + b]);
    float h1 = __half2float(hprev[(((size_t)(u1 & 0xffff)) << 5) + b]);
    float h2 = __half2float(hprev[(((size_t)(u2 & 0xffff)) << 5) + b]);
    float h3 = __half2float(hprev[(((size_t)(u3 & 0xffff)) << 5) + b]);
    a0 += entval(u0) * h0;
    a1 += entval(u1) * h1;
    a2 += entval(u2) * h2;
    a3 += entval(u3) * h3;
  }
  float acc = (a0 + a1) + (a2 + a3);
  acc += __shfl_xor(acc, 32, 64);
  float hv = 1.0f / (1.0f + __expf(-(pre + acc)));
  if (h == 0) hnext[(r << 5) + b] = __float2half_rn(hv);
}

// ---------------- Output spmm, XCD-partitioned by time, fp16 h ----------------
__global__ void __launch_bounds__(256, 8) out_kernel(
    const int* __restrict__ ho_rs, const int* __restrict__ ho_cur,
    const uint32_t* __restrict__ ho_ent,
    const float* __restrict__ ho_bias, const __half* __restrict__ hAll,
    float* __restrict__ out_tmp) {
  int xcd = blockIdx.x & 7;
  int w   = (blockIdx.x >> 3) * 4 + (threadIdx.x >> 6);
  int lane = threadIdx.x & 63;
  int h = lane >> 5, b = lane & 31;
  int t0 = xcd * 4;
  constexpr size_t HS = (size_t)Hh * Bb;
  const __half* hbase = hAll + (size_t)(t0 + 1) * HS;

  for (int o = w; o < Oo; o += 1024) {
    int s0  = __builtin_amdgcn_readfirstlane(ho_rs[o]);
    int cnt = __builtin_amdgcn_readfirstlane(ho_cur[o]) - s0;
    int nb = (cnt + 7) >> 3;
    const int4* ep = (const int4*)(ho_ent + s0);
    float bias = (h == 0) ? ho_bias[o] : 0.f;
    float A0 = bias, A1 = bias, A2 = bias, A3 = bias;
    float B0 = 0.f, B1 = 0.f, B2 = 0.f, B3 = 0.f;
    for (int i = 0; i < nb; i++) {
      int4 e0 = ep[2 * i], e1 = ep[2 * i + 1];
      uint32_t u0 = (uint32_t)(h ? e0.y : e0.x);
      uint32_t u1 = (uint32_t)(h ? e0.w : e0.z);
      uint32_t u2 = (uint32_t)(h ? e1.y : e1.x);
      uint32_t u3 = (uint32_t)(h ? e1.w : e1.z);
      const __half* p0 = hbase + (((size_t)(u0 & 0xffff)) << 5) + b;
      const __half* p1 = hbase + (((size_t)(u1 & 0xffff)) << 5) + b;
      const __half* p2 = hbase + (((size_t)(u2 & 0xffff)) << 5) + b;
      const __half* p3 = hbase + (((size_t)(u3 & 0xffff)) << 5) + b;
      float v0 = entval(u0), v1 = entval(u1), v2 = entval(u2), v3 = entval(u3);
      A0 += v0 * __half2float(p0[0]);
      A1 += v0 * __half2float(p0[HS]);
      A2 += v0 * __half2float(p0[2 * HS]);
      A3 += v0 * __half2float(p0[3 * HS]);
      B0 += v1 * __half2float(p1[0]);
      B1 += v1 * __half2float(p1[HS]);
      B2 += v1 * __half2float(p1[2 * HS]);
      B3 += v1 * __half2float(p1[3 * HS]);
      A0 += v2 * __half2float(p2[0]);
      A1 += v2 * __half2float(p2[HS]);
      A2 += v2 * __half2float(p2[2 * HS]);
      A3 += v2 * __half2float(p2[3 * HS]);
      B0 += v3 * __half2float(p3[0]);
      B1 += v3 * __half2float(p3[HS]);
      B2 += v3 * __half2float(p3[2 * HS]);
      B3 += v3 * __half2float(p3[3 * HS]);
    }
    A0 += B0; A1 += B1; A2 += B2; A3 += B3;
    A0 += __shfl_xor(A0, 32, 64);
    A1 += __shfl_xor(A1, 32, 64);
    A2 += __shfl_xor(A2, 32, 64);
    A3 += __shfl_xor(A3, 32, 64);
    if (h == 0) {
      out_tmp[((size_t)(t0 + 0) * Oo + o) * Bb + b] = A0;
      out_tmp[((size_t)(t0 + 1) * Oo + o) * Bb + b] = A1;
      out_tmp[((size_t)(t0 + 2) * Oo + o) * Bb + b] = A2;
      out_tmp[((size_t)(t0 + 3) * Oo + o) * Bb + b] = A3;
    }
  }
}

// ---------------- out transpose: (T,O,B) -> (B,T,O), fp32 ----------------
__global__ void transpose_out_kernel(const float* __restrict__ out_tmp, float* __restrict__ dout) {
  int blk = blockIdx.x;
  int t  = blk >> 5;
  int o0 = (blk & 31) << 6;
  __shared__ float lds[64][33];
  int tid = threadIdx.x;
  for (int idx = tid; idx < 64 * 32; idx += 256) {
    int ol = idx >> 5, bb = idx & 31;
    lds[ol][bb] = out_tmp[(size_t)t * Oo * Bb + (size_t)(o0 + ol) * Bb + bb];
  }
  __syncthreads();
  for (int idx = tid; idx < 32 * 64; idx += 256) {
    int bb = idx >> 6, ol = idx & 63;
    dout[(size_t)bb * Tt * Oo + (size_t)t * Oo + o0 + ol] = lds[ol][bb];
  }
}

extern "C" void kernel_launch(void* const* d_in, const int* in_sizes, int n_in,
                              void* d_out, int out_size, void* d_ws, size_t ws_size,
                              hipStream_t stream) {
  const float* x       = (const float*)d_in[0];
  const int*   hh_rows = (const int*)d_in[1];
  const int*   hh_cols = (const int*)d_in[2];
  const float* hh_vals = (const float*)d_in[3];
  const float* hh_bias = (const float*)d_in[4];
  const int*   ih_rows = (const int*)d_in[5];
  const int*   ih_cols = (const int*)d_in[6];
  const float* ih_vals = (const float*)d_in[7];
  const int*   ho_rows = (const int*)d_in[8];
  const int*   ho_cols = (const int*)d_in[9];
  const float* ho_vals = (const float*)d_in[10];
  const float* ho_bias = (const float*)d_in[11];
  float* out = (float*)d_out;

  const int nnz_hh = in_sizes[1];
  const int nnz_ih = in_sizes[5];
  const int nnz_ho = in_sizes[8];

  // Workspace carve-up (~70 MB)
  char* w = (char*)d_ws;
  size_t off = 0;
  auto alloc = [&](size_t bytes) -> void* {
    void* p = w + off;
    off += (bytes + 255) & ~(size_t)255;
    return p;
  };
  __half* x2h    = (__half*)alloc(2 * (size_t)Ii * TB);                 // 16 MB
  __half* hAll   = (__half*)alloc(2 * (size_t)(Tt + 1) * Hh * Bb);      // 16.5 MB
  __half* preAll = (__half*)alloc(2 * (size_t)Tt * Hh * Bb);            // 16 MB
  float* out_tmp = (float*)alloc(4 * (size_t)Tt * Oo * Bb);             // 8 MB
  int*  ih_rs  = (int*)alloc(4 * (size_t)(Hh + 1));
  int*  hh_rs  = (int*)alloc(4 * (size_t)(Hh + 1));
  int*  ho_rs  = (int*)alloc(4 * (size_t)(Oo + 1));
  size_t zero_off0 = off;
  int*  cur_all = (int*)alloc(4 * (size_t)(Hh + Hh + Oo));
  int*  ih_cur = cur_all;
  int*  hh_cur = cur_all + Hh;
  int*  ho_cur = cur_all + 2 * Hh;
  size_t zero_bytes = off - zero_off0;
  size_t ent_off0 = off;
  uint32_t* ih_ent = (uint32_t*)alloc(4 * ((size_t)nnz_ih + 8 * Hh + 64));
  uint32_t* hh_ent = (uint32_t*)alloc(4 * ((size_t)nnz_hh + 8 * Hh + 64));
  uint32_t* ho_ent = (uint32_t*)alloc(4 * ((size_t)nnz_ho + 8 * Oo + 64));
  size_t ent_bytes = off - ent_off0;

  // Init (3 memsets)
  hipMemsetAsync(hAll, 0, 2 * (size_t)Hh * Bb, stream);   // h_{-1} = 0
  hipMemsetAsync(w + zero_off0, 0, zero_bytes, stream);
  hipMemsetAsync(w + ent_off0, 0, ent_bytes, stream);     // pad entries = col 0, val 0

  // K1: hist (XCD-filtered, first 512 blocks) ‖ x transpose (2048 blocks)
  k1_hist_transpose<<<SCB + (Tt / 2) * (Ii / 64), 256, 0, stream>>>(
      x, (__half2*)x2h,
      ih_rows, nnz_ih, ih_cur,
      hh_rows, nnz_hh, hh_cur,
      ho_rows, nnz_ho, ho_cur);

  // K2: scan (rows padded to multiples of 8 entries)
  scan3_kernel<<<3, 1024, 0, stream>>>(ih_cur, Hh, ih_rs,
                                       hh_cur, Hh, hh_rs,
                                       ho_cur, Oo, ho_rs);

  // K3: ih scatter (XCD-filtered) — critical path to preih
  k3_scatter_ih<<<SCB, 256, 0, stream>>>(ih_rows, ih_cols, ih_vals, nnz_ih, ih_cur, ih_ent);

  // K4: hh+ho scatter (XCD-filtered, first 512 blocks) ‖ preih (16384 blocks)
  k4_preih_scatter<<<SCB + 8 * Hh / 4, 256, 0, stream>>>(
      ih_rs, ih_cur, ih_ent, hh_bias, x2h, (__half2*)preAll,
      hh_rows, hh_cols, hh_vals, nnz_hh, hh_cur, hh_ent,
      ho_rows, ho_cols, ho_vals, nnz_ho, ho_cur, ho_ent);

  // Recurrence: one dispatch per step
  for (int t = 0; t < Tt; t++) {
    step_kernel<<<Hh / 4, 256, 0, stream>>>(
        hh_rs, hh_cur, hh_ent,
        preAll + (size_t)t * Hh * Bb,
        hAll + (size_t)t * Hh * Bb,
        hAll + (size_t)(t + 1) * Hh * Bb);
  }

  // Output spmm (XCD t-partitioned) + final transpose
  out_kernel<<<2048, 256, 0, stream>>>(
      ho_rs, ho_cur, ho_ent, ho_bias, hAll, out_tmp);
  transpose_out_kernel<<<Tt * (Oo / 64), 256, 0, stream>>>(out_tmp, out);

  (void)n_in; (void)out_size; (void)ws_size;
}